// Round 10
// baseline (80.925 us; speedup 1.0000x reference)
//
#include <hip/hip_runtime.h>
#include <math.h>

#define B_ 16
#define T_ 3000
#define D_ 512
#define NTOK 448
#define LN_EPS 1e-5f

// ws layout (floats):
// [16..32)   diff[b] = |sum_alpha - tgt|
// [64..64+B*T)   cum[b][t]
// [64+B*T ..)    ae[b][448] (int2: start, end)
#define WS_DIFF 16
#define WS_CUM  64
#define WS_AE   (64 + B_ * T_)

struct F8 { float v[8]; };

__device__ inline F8 load8(const float* __restrict__ p) {
    F8 r;
    float4 a = *(const float4*)p;
    float4 b = *(const float4*)(p + 4);
    r.v[0]=a.x; r.v[1]=a.y; r.v[2]=a.z; r.v[3]=a.w;
    r.v[4]=b.x; r.v[5]=b.y; r.v[6]=b.z; r.v[7]=b.w;
    return r;
}

// async global->LDS, 16B per lane; dst is wave-uniform base, HW adds lane*16
__device__ inline void stage16(const float* src, float* dst) {
    __builtin_amdgcn_global_load_lds(
        (const __attribute__((address_space(1))) void*)src,
        (__attribute__((address_space(3))) void*)dst, 16, 0, 0);
}

// ---- Kernel B: conv + LN + linear + sigmoid -> alpha[B,T] ----
__global__ __launch_bounds__(256) void k_alpha(
    const float* __restrict__ enc, const float* __restrict__ convw,
    const float* __restrict__ gamma, const float* __restrict__ beta,
    const float* __restrict__ projw, const float* __restrict__ projb,
    const int* __restrict__ ilen, float* __restrict__ alpha_out)
{
    const int NB = 188;  // blocks per batch (188*16 = 3008 >= T)
    int b  = blockIdx.x / NB;
    int tb = blockIdx.x % NB;
    int t0 = tb * 16;
    int tid = threadIdx.x;
    int wave = tid >> 6;
    int lane = tid & 63;

    int il = ilen[b];
    if (t0 >= il) {                      // whole block masked: zeros, no enc reads
        int t = t0 + tid;
        if (tid < 16 && t < T_) alpha_out[b * T_ + t] = 0.0f;
        return;
    }

    __shared__ float lds[18][512];       // rows t0-1 .. t0+16 (clamped)

    const float* encb = enc + (size_t)b * T_ * D_;
    for (int r = wave; r < 18; r += 4) {
        int t = t0 - 1 + r;
        t = t < 0 ? 0 : (t > T_ - 1 ? T_ - 1 : t);
        const float* src = encb + (size_t)t * D_ + lane * 4;
        stage16(src,       &lds[r][0]);
        stage16(src + 256, &lds[r][256]);
    }

    // per-lane weights while staging is in flight
    int d0 = lane * 8;
    float w24[24];
    const float4* wp = (const float4*)(convw + (size_t)d0 * 3);
#pragma unroll
    for (int i = 0; i < 6; ++i) {
        float4 q = wp[i];
        w24[4*i+0]=q.x; w24[4*i+1]=q.y; w24[4*i+2]=q.z; w24[4*i+3]=q.w;
    }
    F8 pw = load8(projw + d0);
    F8 gm = load8(gamma + d0);
    F8 bt = load8(beta + d0);
    float pg[8];
    float c0p = 0.f, c1p = 0.f;
#pragma unroll
    for (int j = 0; j < 8; ++j) {
        pg[j] = pw.v[j] * gm.v[j];
        c0p += pw.v[j] * bt.v[j];
        c1p += pg[j];
    }

    __syncthreads();                     // vmcnt(0) drain of DMA + barrier

    int w4 = wave * 4;                   // wave handles t = t0+w4 .. t0+w4+3
    float4 ra0 = *(const float4*)&lds[w4][d0];
    float4 ra1 = *(const float4*)&lds[w4][d0 + 4];
    float4 rb0 = *(const float4*)&lds[w4 + 1][d0];
    float4 rb1 = *(const float4*)&lds[w4 + 1][d0 + 4];

    float s1[4], s2[4], sp[4];
#pragma unroll
    for (int q = 0; q < 4; ++q) { s1[q]=0.f; s2[q]=0.f; sp[q]=0.f; }

#pragma unroll
    for (int q = 0; q < 4; ++q) {
        float4 rc0 = *(const float4*)&lds[w4 + q + 2][d0];
        float4 rc1 = *(const float4*)&lds[w4 + q + 2][d0 + 4];
        int t = t0 + w4 + q;
        float m0 = (t == 0)      ? 0.f : 1.f;   // conv zero-pad at edges
        float m2 = (t >= T_ - 1) ? 0.f : 1.f;
        float xm[8] = {ra0.x,ra0.y,ra0.z,ra0.w, ra1.x,ra1.y,ra1.z,ra1.w};
        float xc[8] = {rb0.x,rb0.y,rb0.z,rb0.w, rb1.x,rb1.y,rb1.z,rb1.w};
        float xp[8] = {rc0.x,rc0.y,rc0.z,rc0.w, rc1.x,rc1.y,rc1.z,rc1.w};
#pragma unroll
        for (int j = 0; j < 8; ++j) {
            float y = (xm[j]*m0)*w24[3*j] + xc[j]*w24[3*j+1] + (xp[j]*m2)*w24[3*j+2];
            s1[q] += y; s2[q] += y*y; sp[q] += pg[j]*y;
        }
        ra0 = rb0; ra1 = rb1; rb0 = rc0; rb1 = rc1;
    }

#pragma unroll
    for (int off = 1; off < 64; off <<= 1) {
#pragma unroll
        for (int q = 0; q < 4; ++q) {
            s1[q] += __shfl_xor(s1[q], off);
            s2[q] += __shfl_xor(s2[q], off);
            sp[q] += __shfl_xor(sp[q], off);
        }
        c0p += __shfl_xor(c0p, off);
        c1p += __shfl_xor(c1p, off);
    }
    if (lane == 0) {
        float c0 = c0p + projb[0];
        float c1 = c1p;
#pragma unroll
        for (int q = 0; q < 4; ++q) {
            int t = t0 + w4 + q;
            if (t >= T_) break;
            float mu  = s1[q] * (1.0f / D_);
            float var = s2[q] * (1.0f / D_) - mu * mu;
            float rsig = rsqrtf(var + LN_EPS);
            float logit = rsig * (sp[q] - mu * c1) + c0;
            float a = 1.0f / (1.0f + expf(-logit));
            if (t >= il) a = 0.0f;
            alpha_out[b * T_ + t] = a;
        }
    }
}

// ---- Kernel C: per-batch scan + scale + packed (start,end) per bin ----
__global__ __launch_bounds__(1024) void k_prep(
    const float* __restrict__ alpha, const int* __restrict__ tlen,
    const int* __restrict__ ilen, float* __restrict__ ws)
{
    __shared__ float sc[T_];
    __shared__ float part[16];
    __shared__ int   sstg[452];

    int b = blockIdx.x;
    int tid = threadIdx.x;
    int wave = tid >> 6;
    int lane = tid & 63;

    float* cumg = ws + WS_CUM + (size_t)b * T_;
    int2*  aeg  = (int2*)(ws + WS_AE) + b * NTOK;

    // block-wide inclusive cumsum of alpha (unscaled), 3 chunks of 1024
    float run = 0.f;
    for (int base = 0; base < T_; base += 1024) {
        int t = base + tid;
        float v = (t < T_) ? alpha[b * T_ + t] : 0.f;
#pragma unroll
        for (int off = 1; off < 64; off <<= 1) {
            float n = __shfl_up(v, off);
            if (lane >= off) v += n;
        }
        if (lane == 63) part[wave] = v;
        __syncthreads();
        float prefix = run;
        for (int w = 0; w < 16; ++w) {
            float pv = part[w];
            if (w < wave) prefix += pv;
            run += pv;
        }
        v += prefix;
        if (t < T_) sc[t] = v;
        __syncthreads();
    }

    float sum = run;               // identical in all threads
    float tgt = (float)tlen[b];
    float scale = tgt / fmaxf(sum, 1e-8f);
    if (tid == 0) ws[WS_DIFF + b] = fabsf(sum - tgt);

    // scale in LDS + write cum to global
    for (int t = tid; t < T_; t += 1024) {
        float cv = sc[t] * scale;
        sc[t] = cv;
        cumg[t] = cv;
    }
    __syncthreads();

    // bin starts: sstg[k] = first t with cum[t] >= k, k in [0,449]
    if (tid < 450) {
        float vk = (float)tid;
        int lo = 0, hi = T_;
        while (lo < hi) {
            int mid = (lo + hi) >> 1;
            if (sc[mid] < vk) lo = mid + 1; else hi = mid;
        }
        sstg[tid] = lo;
    }
    __syncthreads();

    int il = ilen[b];
    if (tid < NTOK) {
        int a = sstg[tid];
        int e = sstg[tid + 1] + 1;
        if (e > il) e = il;
        aeg[tid] = make_int2(a, e);
    }
}

// ---- Kernel E: gather, one WAVE per bin, branch-free inner loop ----
// Block = 4 waves = 4 bins. Grid = B*112 + 1 (last block: qty loss).
__global__ __launch_bounds__(256) void k_gather(
    const float* __restrict__ enc, const float* __restrict__ ws,
    float* __restrict__ out, float* __restrict__ qty)
{
    int bid = blockIdx.x;
    if (bid == B_ * 112) {               // qty block
        int lane = threadIdx.x;
        if (lane < 64) {
            float v = (lane < B_) ? ws[WS_DIFF + lane] : 0.f;
#pragma unroll
            for (int off = 1; off < 16; off <<= 1) v += __shfl_xor(v, off);
            if (lane == 0) *qty = v * (1.0f / B_);
        }
        return;
    }

    const int NBLK = NTOK / 4;  // 112
    int b  = bid / NBLK;
    int kg = bid % NBLK;
    int wave = threadIdx.x >> 6;
    int lane = threadIdx.x & 63;
    int k = kg * 4 + wave;

    const float* cb  = ws + WS_CUM + (size_t)b * T_;
    const int2*  aeg = (const int2*)(ws + WS_AE) + b * NTOK;

    int2 ae = aeg[k];
    int a = ae.x, e = ae.y;

    int d0 = lane * 8;
    const float* encb = enc + (size_t)b * T_ * D_ + d0;

    float4 aa = {0,0,0,0}, ab = {0,0,0,0};
    float fk = (float)k;

    for (int base = a; base < e; base += 63) {
        int n = e - base; if (n > 63) n = 63;
        // lane j (j<=n) holds cum[base-1+j]; weight of frame base+j for bin k:
        float cl = 0.0f;
        int t = base - 1 + lane;
        if (lane <= n && t >= 0) cl = cb[t];
        float cn = __shfl_down(cl, 1);
        float fklo = floorf(cl);
        float bnd  = fklo + 1.0f;
        float wlo  = fmaxf(fminf(cn, bnd) - cl, 0.0f);
        float whi  = fmaxf(cn - bnd, 0.0f);
        float wl = (fklo == fk ? wlo : 0.0f) + (floorf(cn) == fk ? whi : 0.0f);
        if (lane >= n) wl = 0.0f;

#pragma unroll 4
        for (int j = 0; j < n; ++j) {
            float w = __shfl(wl, j);
            const float* rp = encb + (size_t)(base + j) * D_;
            float4 ea = *(const float4*)rp;
            float4 eb = *(const float4*)(rp + 4);
            aa.x += ea.x*w; aa.y += ea.y*w; aa.z += ea.z*w; aa.w += ea.w*w;
            ab.x += eb.x*w; ab.y += eb.y*w; ab.z += eb.z*w; ab.w += eb.w*w;
        }
    }

    float* op = out + ((size_t)b * NTOK + k) * D_ + d0;
    *(float4*)op       = aa;
    *(float4*)(op + 4) = ab;
}

extern "C" void kernel_launch(void* const* d_in, const int* in_sizes, int n_in,
                              void* d_out, int out_size, void* d_ws, size_t ws_size,
                              hipStream_t stream) {
    const float* enc   = (const float*)d_in[0];
    const float* convw = (const float*)d_in[1];
    const float* gamma = (const float*)d_in[2];
    const float* beta  = (const float*)d_in[3];
    const float* projw = (const float*)d_in[4];
    const float* projb = (const float*)d_in[5];
    const int*   ilen  = (const int*)d_in[6];
    const int*   tlen  = (const int*)d_in[7];

    float* out_f     = (float*)d_out;                       // [B,448,D]
    float* alpha_out = out_f + (size_t)B_ * NTOK * D_;      // [B,T]
    float* qty_out   = alpha_out + (size_t)B_ * T_;         // scalar

    float* ws = (float*)d_ws;

    hipLaunchKernelGGL(k_alpha, dim3(B_ * 188), dim3(256), 0, stream,
                       enc, convw, gamma, beta, projw, projb, ilen, alpha_out);
    hipLaunchKernelGGL(k_prep, dim3(B_), dim3(1024), 0, stream,
                       alpha_out, tlen, ilen, ws);
    // MEASUREMENT: k_gather launched 3x (idempotent overwrite).
    // dur_us = base + 2*G  ->  G = (dur_us - 47.2) / 2
    hipLaunchKernelGGL(k_gather, dim3(B_ * 112 + 1), dim3(256), 0, stream,
                       enc, ws, out_f, qty_out);
    hipLaunchKernelGGL(k_gather, dim3(B_ * 112 + 1), dim3(256), 0, stream,
                       enc, ws, out_f, qty_out);
    hipLaunchKernelGGL(k_gather, dim3(B_ * 112 + 1), dim3(256), 0, stream,
                       enc, ws, out_f, qty_out);
}

// Round 14
// 48.203 us; speedup vs baseline: 1.6789x; 1.6789x over previous
//
#include <hip/hip_runtime.h>
#include <math.h>

#define B_ 16
#define T_ 3000
#define D_ 512
#define NTOK 448
#define LN_EPS 1e-5f

// ws layout (floats):
// [16..32)   diff[b] = |sum_alpha - tgt|
// [64..64+B*T)   cum[b][t]
// [64+B*T ..)    ae[b][448] (int2: start, end)
#define WS_DIFF 16
#define WS_CUM  64
#define WS_AE   (64 + B_ * T_)

struct F8 { float v[8]; };

__device__ inline F8 load8(const float* __restrict__ p) {
    F8 r;
    float4 a = *(const float4*)p;
    float4 b = *(const float4*)(p + 4);
    r.v[0]=a.x; r.v[1]=a.y; r.v[2]=a.z; r.v[3]=a.w;
    r.v[4]=b.x; r.v[5]=b.y; r.v[6]=b.z; r.v[7]=b.w;
    return r;
}

// async global->LDS, 16B per lane; dst is wave-uniform base, HW adds lane*16
__device__ inline void stage16(const float* src, float* dst) {
    __builtin_amdgcn_global_load_lds(
        (const __attribute__((address_space(1))) void*)src,
        (__attribute__((address_space(3))) void*)dst, 16, 0, 0);
}

// ---- Kernel B: conv + LN + linear + sigmoid -> alpha[B,T] ----
__global__ __launch_bounds__(256) void k_alpha(
    const float* __restrict__ enc, const float* __restrict__ convw,
    const float* __restrict__ gamma, const float* __restrict__ beta,
    const float* __restrict__ projw, const float* __restrict__ projb,
    const int* __restrict__ ilen, float* __restrict__ alpha_out)
{
    const int NB = 188;  // blocks per batch (188*16 = 3008 >= T)
    int b  = blockIdx.x / NB;
    int tb = blockIdx.x % NB;
    int t0 = tb * 16;
    int tid = threadIdx.x;
    int wave = tid >> 6;
    int lane = tid & 63;

    int il = ilen[b];
    if (t0 >= il) {                      // whole block masked: zeros, no enc reads
        int t = t0 + tid;
        if (tid < 16 && t < T_) alpha_out[b * T_ + t] = 0.0f;
        return;
    }

    __shared__ float lds[18][512];       // rows t0-1 .. t0+16 (clamped)

    const float* encb = enc + (size_t)b * T_ * D_;
    for (int r = wave; r < 18; r += 4) {
        int t = t0 - 1 + r;
        t = t < 0 ? 0 : (t > T_ - 1 ? T_ - 1 : t);
        const float* src = encb + (size_t)t * D_ + lane * 4;
        stage16(src,       &lds[r][0]);
        stage16(src + 256, &lds[r][256]);
    }

    // per-lane weights while staging is in flight
    int d0 = lane * 8;
    float w24[24];
    const float4* wp = (const float4*)(convw + (size_t)d0 * 3);
#pragma unroll
    for (int i = 0; i < 6; ++i) {
        float4 q = wp[i];
        w24[4*i+0]=q.x; w24[4*i+1]=q.y; w24[4*i+2]=q.z; w24[4*i+3]=q.w;
    }
    F8 pw = load8(projw + d0);
    F8 gm = load8(gamma + d0);
    F8 bt = load8(beta + d0);
    float pg[8];
    float c0p = 0.f, c1p = 0.f;
#pragma unroll
    for (int j = 0; j < 8; ++j) {
        pg[j] = pw.v[j] * gm.v[j];
        c0p += pw.v[j] * bt.v[j];
        c1p += pg[j];
    }

    __syncthreads();                     // vmcnt(0) drain of DMA + barrier

    int w4 = wave * 4;                   // wave handles t = t0+w4 .. t0+w4+3
    float4 ra0 = *(const float4*)&lds[w4][d0];
    float4 ra1 = *(const float4*)&lds[w4][d0 + 4];
    float4 rb0 = *(const float4*)&lds[w4 + 1][d0];
    float4 rb1 = *(const float4*)&lds[w4 + 1][d0 + 4];

    float s1[4], s2[4], sp[4];
#pragma unroll
    for (int q = 0; q < 4; ++q) { s1[q]=0.f; s2[q]=0.f; sp[q]=0.f; }

#pragma unroll
    for (int q = 0; q < 4; ++q) {
        float4 rc0 = *(const float4*)&lds[w4 + q + 2][d0];
        float4 rc1 = *(const float4*)&lds[w4 + q + 2][d0 + 4];
        int t = t0 + w4 + q;
        float m0 = (t == 0)      ? 0.f : 1.f;   // conv zero-pad at edges
        float m2 = (t >= T_ - 1) ? 0.f : 1.f;
        float xm[8] = {ra0.x,ra0.y,ra0.z,ra0.w, ra1.x,ra1.y,ra1.z,ra1.w};
        float xc[8] = {rb0.x,rb0.y,rb0.z,rb0.w, rb1.x,rb1.y,rb1.z,rb1.w};
        float xp[8] = {rc0.x,rc0.y,rc0.z,rc0.w, rc1.x,rc1.y,rc1.z,rc1.w};
#pragma unroll
        for (int j = 0; j < 8; ++j) {
            float y = (xm[j]*m0)*w24[3*j] + xc[j]*w24[3*j+1] + (xp[j]*m2)*w24[3*j+2];
            s1[q] += y; s2[q] += y*y; sp[q] += pg[j]*y;
        }
        ra0 = rb0; ra1 = rb1; rb0 = rc0; rb1 = rc1;
    }

#pragma unroll
    for (int off = 1; off < 64; off <<= 1) {
#pragma unroll
        for (int q = 0; q < 4; ++q) {
            s1[q] += __shfl_xor(s1[q], off);
            s2[q] += __shfl_xor(s2[q], off);
            sp[q] += __shfl_xor(sp[q], off);
        }
        c0p += __shfl_xor(c0p, off);
        c1p += __shfl_xor(c1p, off);
    }
    if (lane == 0) {
        float c0 = c0p + projb[0];
        float c1 = c1p;
#pragma unroll
        for (int q = 0; q < 4; ++q) {
            int t = t0 + w4 + q;
            if (t >= T_) break;
            float mu  = s1[q] * (1.0f / D_);
            float var = s2[q] * (1.0f / D_) - mu * mu;
            float rsig = rsqrtf(var + LN_EPS);
            float logit = rsig * (sp[q] - mu * c1) + c0;
            float a = 1.0f / (1.0f + expf(-logit));
            if (t >= il) a = 0.0f;
            alpha_out[b * T_ + t] = a;
        }
    }
}

// ---- Kernel C: per-batch scan + scale + packed (start,end) per bin ----
__global__ __launch_bounds__(1024) void k_prep(
    const float* __restrict__ alpha, const int* __restrict__ tlen,
    const int* __restrict__ ilen, float* __restrict__ ws)
{
    __shared__ float sc[T_];
    __shared__ float part[16];
    __shared__ int   sstg[452];

    int b = blockIdx.x;
    int tid = threadIdx.x;
    int wave = tid >> 6;
    int lane = tid & 63;

    float* cumg = ws + WS_CUM + (size_t)b * T_;
    int2*  aeg  = (int2*)(ws + WS_AE) + b * NTOK;

    // block-wide inclusive cumsum of alpha (unscaled), 3 chunks of 1024
    float run = 0.f;
    for (int base = 0; base < T_; base += 1024) {
        int t = base + tid;
        float v = (t < T_) ? alpha[b * T_ + t] : 0.f;
#pragma unroll
        for (int off = 1; off < 64; off <<= 1) {
            float n = __shfl_up(v, off);
            if (lane >= off) v += n;
        }
        if (lane == 63) part[wave] = v;
        __syncthreads();
        float prefix = run;
        for (int w = 0; w < 16; ++w) {
            float pv = part[w];
            if (w < wave) prefix += pv;
            run += pv;
        }
        v += prefix;
        if (t < T_) sc[t] = v;
        __syncthreads();
    }

    float sum = run;               // identical in all threads
    float tgt = (float)tlen[b];
    float scale = tgt / fmaxf(sum, 1e-8f);
    if (tid == 0) ws[WS_DIFF + b] = fabsf(sum - tgt);

    // scale in LDS + write cum to global
    for (int t = tid; t < T_; t += 1024) {
        float cv = sc[t] * scale;
        sc[t] = cv;
        cumg[t] = cv;
    }
    __syncthreads();

    // bin starts: sstg[k] = first t with cum[t] >= k, k in [0,449]
    if (tid < 450) {
        float vk = (float)tid;
        int lo = 0, hi = T_;
        while (lo < hi) {
            int mid = (lo + hi) >> 1;
            if (sc[mid] < vk) lo = mid + 1; else hi = mid;
        }
        sstg[tid] = lo;
    }
    __syncthreads();

    int il = ilen[b];
    if (tid < NTOK) {
        int a = sstg[tid];
        int e = sstg[tid + 1] + 1;
        if (e > il) e = il;
        aeg[tid] = make_int2(a, e);
    }
}

// ---- Kernel E: gather, one WAVE per bin, XCD-swizzled block mapping ----
// 1792 bin-job blocks (4 bins each... actually 4 waves = 4 bins) + 1 qty block.
// Swizzle: job j = (bid%8)*224 + bid/8  ->  each XCD covers exactly 2 batches
// (L2 locality: adjacent bins share boundary rows and the same enc slice).
__global__ __launch_bounds__(256) void k_gather(
    const float* __restrict__ enc, const float* __restrict__ ws,
    float* __restrict__ out, float* __restrict__ qty)
{
    int bid = blockIdx.x;
    if (bid == B_ * 112) {               // qty block
        int lane = threadIdx.x;
        if (lane < 64) {
            float v = (lane < B_) ? ws[WS_DIFF + lane] : 0.f;
#pragma unroll
            for (int off = 1; off < 16; off <<= 1) v += __shfl_xor(v, off);
            if (lane == 0) *qty = v * (1.0f / B_);
        }
        return;
    }

    const int NBLK = NTOK / 4;  // 112 jobs per batch
    int j_  = (bid & 7) * 224 + (bid >> 3);   // XCD-aware remap (1792 = 8*224)
    int b   = j_ / NBLK;
    int kg  = j_ % NBLK;
    int wave = threadIdx.x >> 6;
    int lane = threadIdx.x & 63;
    int k = kg * 4 + wave;

    const float* cb  = ws + WS_CUM + (size_t)b * T_;
    const int2*  aeg = (const int2*)(ws + WS_AE) + b * NTOK;

    int2 ae = aeg[k];
    int a = ae.x, e = ae.y;

    int d0 = lane * 8;
    const float* encb = enc + (size_t)b * T_ * D_ + d0;

    float4 aa = {0,0,0,0}, ab = {0,0,0,0};
    float fk = (float)k;

    for (int base = a; base < e; base += 63) {
        int n = e - base; if (n > 63) n = 63;
        // lane j (j<=n) holds cum[base-1+j]; weight of frame base+j for bin k:
        float cl = 0.0f;
        int t = base - 1 + lane;
        if (lane <= n && t >= 0) cl = cb[t];
        float cn = __shfl_down(cl, 1);
        float fklo = floorf(cl);
        float bnd  = fklo + 1.0f;
        float wlo  = fmaxf(fminf(cn, bnd) - cl, 0.0f);
        float whi  = fmaxf(cn - bnd, 0.0f);
        float wl = (fklo == fk ? wlo : 0.0f) + (floorf(cn) == fk ? whi : 0.0f);
        if (lane >= n) wl = 0.0f;

#pragma unroll 4
        for (int j = 0; j < n; ++j) {
            float w = __shfl(wl, j);
            const float* rp = encb + (size_t)(base + j) * D_;
            float4 ea = *(const float4*)rp;
            float4 eb = *(const float4*)(rp + 4);
            aa.x += ea.x*w; aa.y += ea.y*w; aa.z += ea.z*w; aa.w += ea.w*w;
            ab.x += eb.x*w; ab.y += eb.y*w; ab.z += eb.z*w; ab.w += eb.w*w;
        }
    }

    float* op = out + ((size_t)b * NTOK + k) * D_ + d0;
    *(float4*)op       = aa;
    *(float4*)(op + 4) = ab;
}

extern "C" void kernel_launch(void* const* d_in, const int* in_sizes, int n_in,
                              void* d_out, int out_size, void* d_ws, size_t ws_size,
                              hipStream_t stream) {
    const float* enc   = (const float*)d_in[0];
    const float* convw = (const float*)d_in[1];
    const float* gamma = (const float*)d_in[2];
    const float* beta  = (const float*)d_in[3];
    const float* projw = (const float*)d_in[4];
    const float* projb = (const float*)d_in[5];
    const int*   ilen  = (const int*)d_in[6];
    const int*   tlen  = (const int*)d_in[7];

    float* out_f     = (float*)d_out;                       // [B,448,D]
    float* alpha_out = out_f + (size_t)B_ * NTOK * D_;      // [B,T]
    float* qty_out   = alpha_out + (size_t)B_ * T_;         // scalar

    float* ws = (float*)d_ws;

    hipLaunchKernelGGL(k_alpha, dim3(B_ * 188), dim3(256), 0, stream,
                       enc, convw, gamma, beta, projw, projb, ilen, alpha_out);
    hipLaunchKernelGGL(k_prep, dim3(B_), dim3(1024), 0, stream,
                       alpha_out, tlen, ilen, ws);
    hipLaunchKernelGGL(k_gather, dim3(B_ * 112 + 1), dim3(256), 0, stream,
                       enc, ws, out_f, qty_out);
}